// Round 1
// baseline (31506.046 us; speedup 1.0000x reference)
//
#include <hip/hip_runtime.h>

#define DIM 128

// ---------------------------------------------------------------------------
// Degree histogram for all relations at once: degs layout per relation r:
//   deg_u_r at r*(n_u+n_i), deg_i_r at r*(n_u+n_i)+n_u
// ---------------------------------------------------------------------------
__global__ __launch_bounds__(256) void k_deg(const float* __restrict__ vals,
                                             const int* __restrict__ rows,
                                             const int* __restrict__ cols,
                                             float* __restrict__ degs,
                                             int E, int num_r, int n_u, int n_i) {
    long total = (long)E * num_r;
    for (long idx = blockIdx.x * 256L + threadIdx.x; idx < total;
         idx += (long)gridDim.x * 256L) {
        int r = (int)(idx / E);
        float v = vals[idx];
        size_t base = (size_t)r * (n_u + n_i);
        unsafeAtomicAdd(&degs[base + rows[idx]], v);
        unsafeAtomicAdd(&degs[base + n_u + cols[idx]], v);
    }
}

__global__ __launch_bounds__(256) void k_recip(float* __restrict__ degs, long n) {
    long i = blockIdx.x * 256L + threadIdx.x;
    if (i < n) degs[i] = 1.0f / (degs[i] + 1.0f);
}

// ---------------------------------------------------------------------------
// C[M,128] = A[M,128] @ W[128,128], f32. W staged in LDS (64 KB).
// Block: 256 threads -> 32 rows. Thread: 4 rows x 4 cols register tile.
// ---------------------------------------------------------------------------
__global__ __launch_bounds__(256) void k_gemm(const float* __restrict__ A,
                                              const float* __restrict__ W,
                                              float* __restrict__ C, int M) {
    __shared__ float sW[DIM * DIM];
    int tid = threadIdx.x;
    // stage W: 16384 floats = 4096 float4, 16 per thread
    const float4* W4 = (const float4*)W;
    float4* sW4 = (float4*)sW;
    for (int j = tid; j < DIM * DIM / 4; j += 256) sW4[j] = W4[j];
    __syncthreads();

    int row0 = blockIdx.x * 32;
    if (row0 >= M) return;
    int tx = tid & 31;        // col group: cols 4*tx .. 4*tx+3
    int ty = tid >> 5;        // row group: rows row0 + 4*ty .. +3

    int r0 = row0 + 4 * ty;
    // clamp row reads for tail safety (M % 32 == 0 for this problem)
    int ra = (r0 + 0 < M) ? r0 + 0 : M - 1;
    int rb = (r0 + 1 < M) ? r0 + 1 : M - 1;
    int rc = (r0 + 2 < M) ? r0 + 2 : M - 1;
    int rd = (r0 + 3 < M) ? r0 + 3 : M - 1;
    const float* A0 = A + (size_t)ra * DIM;
    const float* A1 = A + (size_t)rb * DIM;
    const float* A2 = A + (size_t)rc * DIM;
    const float* A3 = A + (size_t)rd * DIM;

    float acc[4][4] = {};
#pragma unroll
    for (int k = 0; k < DIM; k += 4) {
        float4 a0 = *(const float4*)(A0 + k);
        float4 a1 = *(const float4*)(A1 + k);
        float4 a2 = *(const float4*)(A2 + k);
        float4 a3 = *(const float4*)(A3 + k);
        float av[4][4] = {{a0.x, a0.y, a0.z, a0.w},
                          {a1.x, a1.y, a1.z, a1.w},
                          {a2.x, a2.y, a2.z, a2.w},
                          {a3.x, a3.y, a3.z, a3.w}};
#pragma unroll
        for (int kk = 0; kk < 4; ++kk) {
            float4 w = *(const float4*)&sW[(k + kk) * DIM + 4 * tx];
#pragma unroll
            for (int i = 0; i < 4; ++i) {
                acc[i][0] += av[i][kk] * w.x;
                acc[i][1] += av[i][kk] * w.y;
                acc[i][2] += av[i][kk] * w.z;
                acc[i][3] += av[i][kk] * w.w;
            }
        }
    }
#pragma unroll
    for (int i = 0; i < 4; ++i) {
        int row = r0 + i;
        if (row < M) {
            float4 v = make_float4(acc[i][0], acc[i][1], acc[i][2], acc[i][3]);
            *(float4*)&C[(size_t)row * DIM + 4 * tx] = v;
        }
    }
}

// ---------------------------------------------------------------------------
// Scatter: out[dst[e]] += T[src[e]] * (va[e] * div[dst[e]])
// 32 lanes per edge, float4 per lane, f32 atomics.
// ---------------------------------------------------------------------------
__global__ __launch_bounds__(256) void k_scatter(const int* __restrict__ dst_idx,
                                                 const int* __restrict__ src_idx,
                                                 const float* __restrict__ va,
                                                 const float* __restrict__ divv,
                                                 const float* __restrict__ T,
                                                 float* __restrict__ out, int E) {
    int e = blockIdx.x * 8 + (threadIdx.x >> 5);
    if (e >= E) return;
    int lane = threadIdx.x & 31;
    int d = dst_idx[e];
    int s = src_idx[e];
    float scale = va[e] * divv[d];
    float4 t = *(const float4*)&T[(size_t)s * DIM + lane * 4];
    float* o = &out[(size_t)d * DIM + lane * 4];
    unsafeAtomicAdd(o + 0, t.x * scale);
    unsafeAtomicAdd(o + 1, t.y * scale);
    unsafeAtomicAdd(o + 2, t.z * scale);
    unsafeAtomicAdd(o + 3, t.w * scale);
}

__global__ __launch_bounds__(256) void k_leaky_relu(float* __restrict__ x, long n4) {
    long i = blockIdx.x * 256L + threadIdx.x;
    if (i >= n4) return;
    float4 v = ((float4*)x)[i];
    v.x = v.x > 0.f ? v.x : 0.01f * v.x;
    v.y = v.y > 0.f ? v.y : 0.01f * v.y;
    v.z = v.z > 0.f ? v.z : 0.01f * v.z;
    v.w = v.w > 0.f ? v.w : 0.01f * v.w;
    ((float4*)x)[i] = v;
}

// ---------------------------------------------------------------------------
extern "C" void kernel_launch(void* const* d_in, const int* in_sizes, int n_in,
                              void* d_out, int out_size, void* d_ws, size_t ws_size,
                              hipStream_t stream) {
    const float* u_in = (const float*)d_in[0];
    const float* i_in = (const float*)d_in[1];
    const float* Wp   = (const float*)d_in[2];
    const float* Ws   = (const float*)d_in[3];
    const float* vals = (const float*)d_in[4];
    const int*   rows = (const int*)d_in[5];
    const int*   cols = (const int*)d_in[6];

    int n_u   = in_sizes[0] / DIM;
    int n_i   = in_sizes[1] / DIM;
    int num_r = in_sizes[3] / (DIM * DIM);
    int E     = in_sizes[4] / num_r;

    size_t matu = (size_t)n_u * DIM;
    size_t mati = (size_t)n_i * DIM;
    size_t tsz  = ((n_u > n_i ? n_u : n_i)) * (size_t)DIM;
    size_t degN = (size_t)num_r * (n_u + n_i);

    float* ws   = (float*)d_ws;
    float* degs = ws;
    float* T    = ws + ((degN + 3) & ~(size_t)3);
    float* u_ws = T + tsz;
    float* i_ws = u_ws + matu;
    float* out_u = (float*)d_out;
    float* out_i = out_u + matu;

    // --- degree/normalizer precompute (depends only on edges) ---
    hipMemsetAsync(degs, 0, degN * sizeof(float), stream);
    k_deg<<<4096, 256, 0, stream>>>(vals, rows, cols, degs, E, num_r, n_u, n_i);
    k_recip<<<(int)((degN + 255) / 256), 256, 0, stream>>>(degs, (long)degN);

    const float* u_cur = u_in;
    const float* i_cur = i_in;
    int gM_u = (n_u + 31) / 32;
    int gM_i = (n_i + 31) / 32;
    int gSc  = (E + 7) / 8;

    for (int r = 0; r < num_r; ++r) {
        const float* Wr = Ws + (size_t)r * DIM * DIM;
        const float* va = vals + (size_t)r * E;
        const int*   ro = rows + (size_t)r * E;
        const int*   co = cols + (size_t)r * E;
        const float* div_u = degs + (size_t)r * (n_u + n_i);
        const float* div_i = div_u + n_u;
        // parity so that r == num_r-1 always lands in d_out
        int to_out = (((num_r - 1 - r) & 1) == 0);
        float* u_next = to_out ? out_u : u_ws;
        float* i_next = to_out ? out_i : i_ws;

        // ---- u phase: u_next = u_cur@Wp + scatter(T = i_cur@Wr) ----
        k_gemm<<<gM_i, 256, 0, stream>>>(i_cur, Wr, T, n_i);
        k_gemm<<<gM_u, 256, 0, stream>>>(u_cur, Wp, u_next, n_u);
        k_scatter<<<gSc, 256, 0, stream>>>(ro, co, va, div_u, T, u_next, E);
        u_cur = u_next;

        // ---- i phase: i_next = i_cur@Wp + scatter(T = u_cur@Wr) ----
        k_gemm<<<gM_u, 256, 0, stream>>>(u_cur, Wr, T, n_u);
        k_gemm<<<gM_i, 256, 0, stream>>>(i_cur, Wp, i_next, n_i);
        k_scatter<<<gSc, 256, 0, stream>>>(co, ro, va, div_i, T, i_next, E);
        i_cur = i_next;
    }

    long n4 = (long)(matu + mati) / 4;
    k_leaky_relu<<<(int)((n4 + 255) / 256), 256, 0, stream>>>(out_u, n4);
}

// Round 2
// 14298.737 us; speedup vs baseline: 2.2034x; 2.2034x over previous
//
#include <hip/hip_runtime.h>

#define DIM 128
#define LDS_PAD 136   // 136 shorts = 272 B row stride: 16B-aligned, 2-way bank alias (free)

typedef __attribute__((ext_vector_type(8))) short short8;
typedef __attribute__((ext_vector_type(4))) float f32x4;

static __device__ inline short f2bf(float f) {
    unsigned u = __builtin_bit_cast(unsigned, f);
    unsigned r = (u + 0x7FFF + ((u >> 16) & 1)) >> 16;  // RNE
    return (short)r;
}

// ---------------------------------------------------------------------------
// Degree histogram for all relations at once.
// ---------------------------------------------------------------------------
__global__ __launch_bounds__(256) void k_deg(const float* __restrict__ vals,
                                             const int* __restrict__ rows,
                                             const int* __restrict__ cols,
                                             float* __restrict__ degs,
                                             int E, int num_r, int n_u, int n_i) {
    long total = (long)E * num_r;
    for (long idx = blockIdx.x * 256L + threadIdx.x; idx < total;
         idx += (long)gridDim.x * 256L) {
        int r = (int)(idx / E);
        float v = vals[idx];
        size_t base = (size_t)r * (n_u + n_i);
        unsafeAtomicAdd(&degs[base + rows[idx]], v);
        unsafeAtomicAdd(&degs[base + n_u + cols[idx]], v);
    }
}

__global__ __launch_bounds__(256) void k_recip(float* __restrict__ degs, long n) {
    long i = blockIdx.x * 256L + threadIdx.x;
    if (i < n) degs[i] = 1.0f / (degs[i] + 1.0f);
}

// ---------------------------------------------------------------------------
// Transpose + convert the 5 weight matrices (Wp, Ws[0..3]) to bf16:
// Wt[mat][n][k] = W[mat][k][n]. Contiguous-k rows so GEMM B-fragments are
// single ds_read_b128s.
// ---------------------------------------------------------------------------
__global__ __launch_bounds__(256) void k_prep_w(const float* __restrict__ Wp,
                                                const float* __restrict__ Ws,
                                                short* __restrict__ Wt,
                                                int num_r) {
    int idx = blockIdx.x * 256 + threadIdx.x;
    int total = (1 + num_r) * DIM * DIM;
    if (idx >= total) return;
    int mat = idx >> 14;            // /16384
    int rem = idx & 16383;
    int n = rem >> 7;
    int k = rem & 127;
    const float* src = (mat == 0) ? Wp : (Ws + (size_t)(mat - 1) * DIM * DIM);
    Wt[idx] = f2bf(src[(size_t)k * DIM + n]);
}

// ---------------------------------------------------------------------------
// C[M,128] = A[M,128] @ W[128,128]  (A f32 -> bf16 on stage, MFMA 16x16x32,
// f32 out). Wt is the pre-transposed bf16 weight [n][k]. Persistent blocks,
// 128-row chunks, 4 waves x (32 rows x 128 cols).
// ---------------------------------------------------------------------------
__global__ __launch_bounds__(256) void k_gemm_mfma(const float* __restrict__ A,
                                                   const short* __restrict__ Wt,
                                                   float* __restrict__ C, int M) {
    __shared__ short sA[DIM * LDS_PAD];
    __shared__ short sW[DIM * LDS_PAD];

    int tid = threadIdx.x;
    int lane = tid & 63;
    int w = tid >> 6;          // wave 0..3
    int m = lane & 15;
    int q = lane >> 4;         // quad 0..3

    // ---- stage Wt (bf16, contiguous) into padded LDS: once per block ----
    for (int j = tid; j < DIM * DIM / 8; j += 256) {   // 2048 groups of 8 shorts
        int row = j >> 4;           // n
        int c8 = (j & 15) * 8;      // k
        int4 v = *(const int4*)&Wt[row * DIM + c8];
        *(int4*)&sW[row * LDS_PAD + c8] = v;
    }

    int nchunks = (M + DIM - 1) / DIM;
    for (int chunk = blockIdx.x; chunk < nchunks; chunk += gridDim.x) {
        int row0 = chunk * DIM;
        __syncthreads();   // prior chunk's LDS reads done (also covers sW 1st iter)
        // ---- stage A chunk: f32 global -> bf16 LDS ----
        for (int j = tid; j < DIM * DIM / 4; j += 256) {  // 4096 groups of 4
            int row = j >> 5;
            int c4 = (j & 31) * 4;
            int grow = row0 + row;
            if (grow >= M) grow = M - 1;                  // clamp (stores guarded)
            float4 v = *(const float4*)&A[(size_t)grow * DIM + c4];
            short4 s = make_short4(f2bf(v.x), f2bf(v.y), f2bf(v.z), f2bf(v.w));
            *(short4*)&sA[row * LDS_PAD + c4] = s;
        }
        __syncthreads();

        // ---- MFMA: wave w does rows [32w, 32w+32) x all 128 cols ----
        f32x4 acc[2][8];
#pragma unroll
        for (int i = 0; i < 2; ++i)
#pragma unroll
            for (int j = 0; j < 8; ++j) acc[i][j] = (f32x4){0.f, 0.f, 0.f, 0.f};

#pragma unroll
        for (int kt = 0; kt < 4; ++kt) {
            int k0 = kt * 32 + q * 8;
            short8 a0 = *(const short8*)&sA[(w * 32 + m) * LDS_PAD + k0];
            short8 a1 = *(const short8*)&sA[(w * 32 + 16 + m) * LDS_PAD + k0];
#pragma unroll
            for (int j = 0; j < 8; ++j) {
                short8 b = *(const short8*)&sW[(j * 16 + m) * LDS_PAD + k0];
                acc[0][j] = __builtin_amdgcn_mfma_f32_16x16x32_bf16(a0, b, acc[0][j], 0, 0, 0);
                acc[1][j] = __builtin_amdgcn_mfma_f32_16x16x32_bf16(a1, b, acc[1][j], 0, 0, 0);
            }
        }

        // ---- store: C/D layout col=lane&15, row=q*4+reg ----
#pragma unroll
        for (int i = 0; i < 2; ++i) {
#pragma unroll
            for (int r = 0; r < 4; ++r) {
                int row = row0 + w * 32 + i * 16 + q * 4 + r;
                if (row < M) {
#pragma unroll
                    for (int j = 0; j < 8; ++j) {
                        C[(size_t)row * DIM + j * 16 + m] = acc[i][j][r];
                    }
                }
            }
        }
    }
}

// ---------------------------------------------------------------------------
// Scatter: out[dst[e]] += T[src[e]] * (va[e] * div[dst[e]])
// ---------------------------------------------------------------------------
__global__ __launch_bounds__(256) void k_scatter(const int* __restrict__ dst_idx,
                                                 const int* __restrict__ src_idx,
                                                 const float* __restrict__ va,
                                                 const float* __restrict__ divv,
                                                 const float* __restrict__ T,
                                                 float* __restrict__ out, int E) {
    int e = blockIdx.x * 8 + (threadIdx.x >> 5);
    if (e >= E) return;
    int lane = threadIdx.x & 31;
    int d = dst_idx[e];
    int s = src_idx[e];
    float scale = va[e] * divv[d];
    float4 t = *(const float4*)&T[(size_t)s * DIM + lane * 4];
    float* o = &out[(size_t)d * DIM + lane * 4];
    unsafeAtomicAdd(o + 0, t.x * scale);
    unsafeAtomicAdd(o + 1, t.y * scale);
    unsafeAtomicAdd(o + 2, t.z * scale);
    unsafeAtomicAdd(o + 3, t.w * scale);
}

__global__ __launch_bounds__(256) void k_leaky_relu(float* __restrict__ x, long n4) {
    long i = blockIdx.x * 256L + threadIdx.x;
    if (i >= n4) return;
    float4 v = ((float4*)x)[i];
    v.x = v.x > 0.f ? v.x : 0.01f * v.x;
    v.y = v.y > 0.f ? v.y : 0.01f * v.y;
    v.z = v.z > 0.f ? v.z : 0.01f * v.z;
    v.w = v.w > 0.f ? v.w : 0.01f * v.w;
    ((float4*)x)[i] = v;
}

// ---------------------------------------------------------------------------
extern "C" void kernel_launch(void* const* d_in, const int* in_sizes, int n_in,
                              void* d_out, int out_size, void* d_ws, size_t ws_size,
                              hipStream_t stream) {
    const float* u_in = (const float*)d_in[0];
    const float* i_in = (const float*)d_in[1];
    const float* Wp   = (const float*)d_in[2];
    const float* Ws   = (const float*)d_in[3];
    const float* vals = (const float*)d_in[4];
    const int*   rows = (const int*)d_in[5];
    const int*   cols = (const int*)d_in[6];

    int n_u   = in_sizes[0] / DIM;
    int n_i   = in_sizes[1] / DIM;
    int num_r = in_sizes[3] / (DIM * DIM);
    int E     = in_sizes[4] / num_r;

    size_t matu = (size_t)n_u * DIM;
    size_t mati = (size_t)n_i * DIM;
    size_t tsz  = ((n_u > n_i ? n_u : n_i)) * (size_t)DIM;
    size_t degN = (size_t)num_r * (n_u + n_i);

    float* ws   = (float*)d_ws;
    float* degs = ws;
    float* T    = ws + ((degN + 3) & ~(size_t)3);
    float* u_ws = T + tsz;
    float* i_ws = u_ws + matu;
    short* Wt   = (short*)(i_ws + mati);   // (1+num_r)*128*128 bf16
    float* out_u = (float*)d_out;
    float* out_i = out_u + matu;

    // --- degree/normalizer precompute ---
    hipMemsetAsync(degs, 0, degN * sizeof(float), stream);
    k_deg<<<4096, 256, 0, stream>>>(vals, rows, cols, degs, E, num_r, n_u, n_i);
    k_recip<<<(int)((degN + 255) / 256), 256, 0, stream>>>(degs, (long)degN);

    // --- weight transpose+convert (once) ---
    int wtot = (1 + num_r) * DIM * DIM;
    k_prep_w<<<(wtot + 255) / 256, 256, 0, stream>>>(Wp, Ws, Wt, num_r);
    const short* Wt_p = Wt;                       // Wp^T bf16
    // Wt_s(r) = Wt + (1+r)*16384

    const float* u_cur = u_in;
    const float* i_cur = i_in;
    int gSc = (E + 7) / 8;
    const int GGEMM = 512;   // 2 blocks/CU (70 KB LDS), persistent chunks

    for (int r = 0; r < num_r; ++r) {
        const short* Wt_r = Wt + (size_t)(1 + r) * DIM * DIM;
        const float* va = vals + (size_t)r * E;
        const int*   ro = rows + (size_t)r * E;
        const int*   co = cols + (size_t)r * E;
        const float* div_u = degs + (size_t)r * (n_u + n_i);
        const float* div_i = div_u + n_u;
        int to_out = (((num_r - 1 - r) & 1) == 0);
        float* u_next = to_out ? out_u : u_ws;
        float* i_next = to_out ? out_i : i_ws;

        // ---- u phase ----
        k_gemm_mfma<<<GGEMM, 256, 0, stream>>>(i_cur, Wt_r, T, n_i);
        k_gemm_mfma<<<GGEMM, 256, 0, stream>>>(u_cur, Wt_p, u_next, n_u);
        k_scatter<<<gSc, 256, 0, stream>>>(ro, co, va, div_u, T, u_next, E);
        u_cur = u_next;

        // ---- i phase ----
        k_gemm_mfma<<<GGEMM, 256, 0, stream>>>(u_cur, Wt_r, T, n_u);
        k_gemm_mfma<<<GGEMM, 256, 0, stream>>>(i_cur, Wt_p, i_next, n_i);
        k_scatter<<<gSc, 256, 0, stream>>>(co, ro, va, div_i, T, i_next, E);
        i_cur = i_next;
    }

    long n4 = (long)(matu + mati) / 4;
    k_leaky_relu<<<(int)((n4 + 255) / 256), 256, 0, stream>>>(out_u, n4);
}

// Round 3
// 2489.922 us; speedup vs baseline: 12.6534x; 5.7426x over previous
//
#include <hip/hip_runtime.h>

#define DIM 128
#define LDS_PAD 136   // shorts; 272 B row stride: 16B-aligned, 2-way bank alias (free)
#define SCAN_T 256
#define SCAN_E 8
#define SCAN_C (SCAN_T * SCAN_E)   // 2048 elems per scan block

typedef __attribute__((ext_vector_type(8))) short short8;
typedef __attribute__((ext_vector_type(4))) float f32x4;

static __device__ inline short f2bf(float f) {
    unsigned u = __builtin_bit_cast(unsigned, f);
    unsigned r = (u + 0x7FFF + ((u >> 16) & 1)) >> 16;  // RNE
    return (short)r;
}

// ---------------------------------------------------------------------------
// Float degree histogram (for div = 1/(seg_sum(va)+1)), all relations.
// ---------------------------------------------------------------------------
__global__ __launch_bounds__(256) void k_deg(const float* __restrict__ vals,
                                             const int* __restrict__ rows,
                                             const int* __restrict__ cols,
                                             float* __restrict__ degs,
                                             int E, int num_r, int n_u, int n_i) {
    long total = (long)E * num_r;
    for (long idx = blockIdx.x * 256L + threadIdx.x; idx < total;
         idx += (long)gridDim.x * 256L) {
        int r = (int)(idx / E);
        float v = vals[idx];
        size_t base = (size_t)r * (n_u + n_i);
        unsafeAtomicAdd(&degs[base + rows[idx]], v);
        unsafeAtomicAdd(&degs[base + n_u + cols[idx]], v);
    }
}

__global__ __launch_bounds__(256) void k_recip(float* __restrict__ degs, long n) {
    long i = blockIdx.x * 256L + threadIdx.x;
    if (i < n) degs[i] = 1.0f / (degs[i] + 1.0f);
}

// ---------------------------------------------------------------------------
// Weight transpose + f32->bf16: Wt[mat][n][k] = W[mat][k][n]
// ---------------------------------------------------------------------------
__global__ __launch_bounds__(256) void k_prep_w(const float* __restrict__ Wp,
                                                const float* __restrict__ Ws,
                                                short* __restrict__ Wt,
                                                int num_r) {
    int idx = blockIdx.x * 256 + threadIdx.x;
    int total = (1 + num_r) * DIM * DIM;
    if (idx >= total) return;
    int mat = idx >> 14;
    int rem = idx & 16383;
    int n = rem >> 7;
    int k = rem & 127;
    const float* src = (mat == 0) ? Wp : (Ws + (size_t)(mat - 1) * DIM * DIM);
    Wt[idx] = f2bf(src[(size_t)k * DIM + n]);
}

// ---------------------------------------------------------------------------
// C[M,128] = A[M,128] @ W  (bf16 MFMA 16x16x32, f32 in/out), persistent blocks
// ---------------------------------------------------------------------------
__global__ __launch_bounds__(256) void k_gemm_mfma(const float* __restrict__ A,
                                                   const short* __restrict__ Wt,
                                                   float* __restrict__ C, int M) {
    __shared__ short sA[DIM * LDS_PAD];
    __shared__ short sW[DIM * LDS_PAD];

    int tid = threadIdx.x;
    int lane = tid & 63;
    int w = tid >> 6;
    int m = lane & 15;
    int q = lane >> 4;

    for (int j = tid; j < DIM * DIM / 8; j += 256) {
        int row = j >> 4;
        int c8 = (j & 15) * 8;
        int4 v = *(const int4*)&Wt[row * DIM + c8];
        *(int4*)&sW[row * LDS_PAD + c8] = v;
    }

    int nchunks = (M + DIM - 1) / DIM;
    for (int chunk = blockIdx.x; chunk < nchunks; chunk += gridDim.x) {
        int row0 = chunk * DIM;
        __syncthreads();
        for (int j = tid; j < DIM * DIM / 4; j += 256) {
            int row = j >> 5;
            int c4 = (j & 31) * 4;
            int grow = row0 + row;
            if (grow >= M) grow = M - 1;
            float4 v = *(const float4*)&A[(size_t)grow * DIM + c4];
            short4 s = make_short4(f2bf(v.x), f2bf(v.y), f2bf(v.z), f2bf(v.w));
            *(short4*)&sA[row * LDS_PAD + c4] = s;
        }
        __syncthreads();

        f32x4 acc[2][8];
#pragma unroll
        for (int i = 0; i < 2; ++i)
#pragma unroll
            for (int j = 0; j < 8; ++j) acc[i][j] = (f32x4){0.f, 0.f, 0.f, 0.f};

#pragma unroll
        for (int kt = 0; kt < 4; ++kt) {
            int k0 = kt * 32 + q * 8;
            short8 a0 = *(const short8*)&sA[(w * 32 + m) * LDS_PAD + k0];
            short8 a1 = *(const short8*)&sA[(w * 32 + 16 + m) * LDS_PAD + k0];
#pragma unroll
            for (int j = 0; j < 8; ++j) {
                short8 b = *(const short8*)&sW[(j * 16 + m) * LDS_PAD + k0];
                acc[0][j] = __builtin_amdgcn_mfma_f32_16x16x32_bf16(a0, b, acc[0][j], 0, 0, 0);
                acc[1][j] = __builtin_amdgcn_mfma_f32_16x16x32_bf16(a1, b, acc[1][j], 0, 0, 0);
            }
        }

#pragma unroll
        for (int i = 0; i < 2; ++i) {
#pragma unroll
            for (int r = 0; r < 4; ++r) {
                int row = row0 + w * 32 + i * 16 + q * 4 + r;
                if (row < M) {
#pragma unroll
                    for (int j = 0; j < 8; ++j) {
                        C[(size_t)row * DIM + j * 16 + m] = acc[i][j][r];
                    }
                }
            }
        }
    }
}

// ---------------------------------------------------------------------------
// CSR build: count -> scan (3 kernels) -> fill
// ---------------------------------------------------------------------------
__global__ __launch_bounds__(256) void k_count(const int* __restrict__ ro,
                                               const int* __restrict__ co,
                                               int* __restrict__ cnt_u,
                                               int* __restrict__ cnt_i, int E) {
    int e = blockIdx.x * 256 + threadIdx.x;
    if (e >= E) return;
    atomicAdd(&cnt_u[ro[e]], 1);
    atomicAdd(&cnt_i[co[e]], 1);
}

__global__ __launch_bounds__(SCAN_T) void k_scan1(const int* __restrict__ cnt,
                                                  int* __restrict__ out,
                                                  int* __restrict__ tot, int n) {
    __shared__ int s[SCAN_T];
    int tid = threadIdx.x;
    int base = blockIdx.x * SCAN_C + tid * SCAN_E;
    int v[SCAN_E];
    int sum = 0;
#pragma unroll
    for (int i = 0; i < SCAN_E; ++i) {
        v[i] = (base + i < n) ? cnt[base + i] : 0;
        sum += v[i];
    }
    s[tid] = sum;
    __syncthreads();
    for (int off = 1; off < SCAN_T; off <<= 1) {
        int t = (tid >= off) ? s[tid - off] : 0;
        __syncthreads();
        s[tid] += t;
        __syncthreads();
    }
    int run = s[tid] - sum;  // exclusive base for this thread within chunk
    if (tid == SCAN_T - 1) tot[blockIdx.x] = s[tid];
#pragma unroll
    for (int i = 0; i < SCAN_E; ++i) {
        if (base + i < n) out[base + i] = run;
        run += v[i];
    }
}

__global__ __launch_bounds__(64) void k_scan2(int* __restrict__ tot, int nchunks) {
    int lane = threadIdx.x;
    int running = 0;
    for (int c0 = 0; c0 < nchunks; c0 += 64) {
        int idx = c0 + lane;
        int orig = (idx < nchunks) ? tot[idx] : 0;
        int v = orig;
#pragma unroll
        for (int d = 1; d < 64; d <<= 1) {
            int t = __shfl_up(v, d);
            if (lane >= d) v += t;
        }
        if (idx < nchunks) tot[idx] = running + v - orig;  // exclusive
        running += __shfl(v, 63);
    }
}

__global__ __launch_bounds__(256) void k_scan3(int* __restrict__ off,
                                               int* __restrict__ cur,
                                               const int* __restrict__ tot,
                                               int n, int E) {
    int i = blockIdx.x * 256 + threadIdx.x;
    if (i < n) {
        int v = off[i] + tot[i / SCAN_C];
        off[i] = v;
        cur[i] = v;
    }
    if (i == 0) off[n] = E;
}

__global__ __launch_bounds__(256) void k_fill(const int* __restrict__ ro,
                                              const int* __restrict__ co,
                                              const float* __restrict__ va,
                                              int* __restrict__ cur_u,
                                              int* __restrict__ cur_i,
                                              int* __restrict__ srcu,
                                              float* __restrict__ valu,
                                              int* __restrict__ srci,
                                              float* __restrict__ vali, int E) {
    int e = blockIdx.x * 256 + threadIdx.x;
    if (e >= E) return;
    int r = ro[e], c = co[e];
    float v = va[e];
    int pu = atomicAdd(&cur_u[r], 1);
    srcu[pu] = c;
    valu[pu] = v;
    int pi = atomicAdd(&cur_i[c], 1);
    srci[pi] = r;
    vali[pi] = v;
}

// ---------------------------------------------------------------------------
// Gather-reduce: out[dst] += div[dst] * sum_e va_e * T[src_e]
// One 32-lane half-wave per dst row; float4 per lane; no atomics.
// ---------------------------------------------------------------------------
__global__ __launch_bounds__(256) void k_gather(const int* __restrict__ off,
                                                const int* __restrict__ csrc,
                                                const float* __restrict__ cval,
                                                const float* __restrict__ divv,
                                                const float* __restrict__ T,
                                                float* __restrict__ out, int n) {
    int dst = blockIdx.x * 8 + (threadIdx.x >> 5);
    if (dst >= n) return;
    int l = threadIdx.x & 31;
    int s0 = off[dst], s1 = off[dst + 1];
    float4 acc = make_float4(0.f, 0.f, 0.f, 0.f);
    for (int j = s0; j < s1; ++j) {
        int s = csrc[j];
        float v = cval[j];
        float4 t = *(const float4*)&T[(size_t)s * DIM + l * 4];
        acc.x += v * t.x;
        acc.y += v * t.y;
        acc.z += v * t.z;
        acc.w += v * t.w;
    }
    float dv = divv[dst];
    float4* op = (float4*)&out[(size_t)dst * DIM + l * 4];
    float4 o = *op;
    o.x += dv * acc.x;
    o.y += dv * acc.y;
    o.z += dv * acc.z;
    o.w += dv * acc.w;
    *op = o;
}

__global__ __launch_bounds__(256) void k_leaky_relu(float* __restrict__ x, long n4) {
    long i = blockIdx.x * 256L + threadIdx.x;
    if (i >= n4) return;
    float4 v = ((float4*)x)[i];
    v.x = v.x > 0.f ? v.x : 0.01f * v.x;
    v.y = v.y > 0.f ? v.y : 0.01f * v.y;
    v.z = v.z > 0.f ? v.z : 0.01f * v.z;
    v.w = v.w > 0.f ? v.w : 0.01f * v.w;
    ((float4*)x)[i] = v;
}

// ---------------------------------------------------------------------------
static inline size_t align4(size_t x) { return (x + 3) & ~(size_t)3; }

extern "C" void kernel_launch(void* const* d_in, const int* in_sizes, int n_in,
                              void* d_out, int out_size, void* d_ws, size_t ws_size,
                              hipStream_t stream) {
    const float* u_in = (const float*)d_in[0];
    const float* i_in = (const float*)d_in[1];
    const float* Wp   = (const float*)d_in[2];
    const float* Ws   = (const float*)d_in[3];
    const float* vals = (const float*)d_in[4];
    const int*   rows = (const int*)d_in[5];
    const int*   cols = (const int*)d_in[6];

    int n_u   = in_sizes[0] / DIM;
    int n_i   = in_sizes[1] / DIM;
    int num_r = in_sizes[3] / (DIM * DIM);
    int E     = in_sizes[4] / num_r;

    size_t matu = (size_t)n_u * DIM;
    size_t mati = (size_t)n_i * DIM;
    size_t tsz  = ((n_u > n_i ? n_u : n_i)) * (size_t)DIM;
    size_t degN = (size_t)num_r * (n_u + n_i);

    // ---- workspace layout (all 4-byte words, 16B-aligned sections) ----
    float* ws = (float*)d_ws;
    size_t o = 0;
    float* degs = ws + o;          o += align4(degN);
    float* T    = ws + o;          o += align4(tsz);
    float* u_ws = ws + o;          o += align4(matu);
    float* i_ws = ws + o;          o += align4(mati);
    short* Wt   = (short*)(ws + o); o += align4((size_t)(1 + num_r) * DIM * DIM / 2);
    int* cnt_u  = (int*)(ws + o);  o += align4(n_u);
    int* off_u  = (int*)(ws + o);  o += align4(n_u + 1);
    int* cur_u  = (int*)(ws + o);  o += align4(n_u);
    int* cnt_i  = (int*)(ws + o);  o += align4(n_i);
    int* off_i  = (int*)(ws + o);  o += align4(n_i + 1);
    int* cur_i  = (int*)(ws + o);  o += align4(n_i);
    int* tot    = (int*)(ws + o);  o += 4096;
    int*   csr_src_u = (int*)(ws + o);   o += align4(E);
    float* csr_val_u = ws + o;           o += align4(E);
    int*   csr_src_i = (int*)(ws + o);   o += align4(E);
    float* csr_val_i = ws + o;           o += align4(E);

    float* out_u = (float*)d_out;
    float* out_i = out_u + matu;

    // ---- degree/normalizer precompute ----
    hipMemsetAsync(degs, 0, degN * sizeof(float), stream);
    k_deg<<<4096, 256, 0, stream>>>(vals, rows, cols, degs, E, num_r, n_u, n_i);
    k_recip<<<(int)((degN + 255) / 256), 256, 0, stream>>>(degs, (long)degN);

    // ---- weight transpose+convert (once) ----
    int wtot = (1 + num_r) * DIM * DIM;
    k_prep_w<<<(wtot + 255) / 256, 256, 0, stream>>>(Wp, Ws, Wt, num_r);
    const short* Wt_p = Wt;

    const float* u_cur = u_in;
    const float* i_cur = i_in;
    int gE = (E + 255) / 256;
    int nch_u = (n_u + SCAN_C - 1) / SCAN_C;
    int nch_i = (n_i + SCAN_C - 1) / SCAN_C;
    const int GGEMM = 512;

    for (int r = 0; r < num_r; ++r) {
        const short* Wt_r = Wt + (size_t)(1 + r) * DIM * DIM;
        const float* va = vals + (size_t)r * E;
        const int*   ro = rows + (size_t)r * E;
        const int*   co = cols + (size_t)r * E;
        const float* div_u = degs + (size_t)r * (n_u + n_i);
        const float* div_i = div_u + n_u;
        int to_out = (((num_r - 1 - r) & 1) == 0);
        float* u_next = to_out ? out_u : u_ws;
        float* i_next = to_out ? out_i : i_ws;

        // ---- build both CSRs for this relation ----
        hipMemsetAsync(cnt_u, 0, (size_t)n_u * sizeof(int), stream);
        hipMemsetAsync(cnt_i, 0, (size_t)n_i * sizeof(int), stream);
        k_count<<<gE, 256, 0, stream>>>(ro, co, cnt_u, cnt_i, E);
        k_scan1<<<nch_u, SCAN_T, 0, stream>>>(cnt_u, off_u, tot, n_u);
        k_scan2<<<1, 64, 0, stream>>>(tot, nch_u);
        k_scan3<<<(n_u + 255) / 256, 256, 0, stream>>>(off_u, cur_u, tot, n_u, E);
        k_scan1<<<nch_i, SCAN_T, 0, stream>>>(cnt_i, off_i, tot, n_i);
        k_scan2<<<1, 64, 0, stream>>>(tot, nch_i);
        k_scan3<<<(n_i + 255) / 256, 256, 0, stream>>>(off_i, cur_i, tot, n_i, E);
        k_fill<<<gE, 256, 0, stream>>>(ro, co, va, cur_u, cur_i,
                                       csr_src_u, csr_val_u, csr_src_i, csr_val_i, E);

        // ---- u phase: u_next = u_cur@Wp + div_u * (A_r @ (i_cur@Wr)) ----
        k_gemm_mfma<<<GGEMM, 256, 0, stream>>>(i_cur, Wt_r, T, n_i);
        k_gemm_mfma<<<GGEMM, 256, 0, stream>>>(u_cur, Wt_p, u_next, n_u);
        k_gather<<<(n_u + 7) / 8, 256, 0, stream>>>(off_u, csr_src_u, csr_val_u,
                                                    div_u, T, u_next, n_u);
        u_cur = u_next;

        // ---- i phase ----
        k_gemm_mfma<<<GGEMM, 256, 0, stream>>>(u_cur, Wt_r, T, n_u);
        k_gemm_mfma<<<GGEMM, 256, 0, stream>>>(i_cur, Wt_p, i_next, n_i);
        k_gather<<<(n_i + 7) / 8, 256, 0, stream>>>(off_i, csr_src_i, csr_val_i,
                                                    div_i, T, i_next, n_i);
        i_cur = i_next;
    }

    long n4 = (long)(matu + mati) / 4;
    k_leaky_relu<<<(int)((n4 + 255) / 256), 256, 0, stream>>>(out_u, n4);
}

// Round 4
// 2132.851 us; speedup vs baseline: 14.7718x; 1.1674x over previous
//
#include <hip/hip_runtime.h>

#define DIM 128
#define LDS_PAD 136   // shorts; 272 B row stride: 16B-aligned, 2-way bank alias (free)
#define SCAN_T 256
#define SCAN_E 8
#define SCAN_C (SCAN_T * SCAN_E)   // 2048 elems per scan block

typedef __attribute__((ext_vector_type(8))) short short8;
typedef __attribute__((ext_vector_type(4))) float f32x4;

static __device__ inline short f2bf(float f) {
    unsigned u = __builtin_bit_cast(unsigned, f);
    unsigned r = (u + 0x7FFF + ((u >> 16) & 1)) >> 16;  // RNE
    return (short)r;
}
static __device__ inline float bf2f(short s) {
    unsigned u = ((unsigned)(unsigned short)s) << 16;
    return __builtin_bit_cast(float, u);
}

// ---------------------------------------------------------------------------
// Weight transpose + f32->bf16: Wt[mat][n][k] = W[mat][k][n]
// ---------------------------------------------------------------------------
__global__ __launch_bounds__(256) void k_prep_w(const float* __restrict__ Wp,
                                                const float* __restrict__ Ws,
                                                short* __restrict__ Wt,
                                                int num_r) {
    int idx = blockIdx.x * 256 + threadIdx.x;
    int total = (1 + num_r) * DIM * DIM;
    if (idx >= total) return;
    int mat = idx >> 14;
    int rem = idx & 16383;
    int n = rem >> 7;
    int k = rem & 127;
    const float* src = (mat == 0) ? Wp : (Ws + (size_t)(mat - 1) * DIM * DIM);
    Wt[idx] = f2bf(src[(size_t)k * DIM + n]);
}

// ---------------------------------------------------------------------------
// C[M,128] = A[M,128] @ W  (bf16 MFMA 16x16x32), OUT = float (self path)
// or short/bf16 (message path T, halves gather traffic). Persistent blocks.
// ---------------------------------------------------------------------------
template <typename OUT>
__global__ __launch_bounds__(256) void k_gemm_mfma(const float* __restrict__ A,
                                                   const short* __restrict__ Wt,
                                                   OUT* __restrict__ C, int M) {
    __shared__ short sA[DIM * LDS_PAD];
    __shared__ short sW[DIM * LDS_PAD];

    int tid = threadIdx.x;
    int lane = tid & 63;
    int w = tid >> 6;
    int m = lane & 15;
    int q = lane >> 4;

    for (int j = tid; j < DIM * DIM / 8; j += 256) {
        int row = j >> 4;
        int c8 = (j & 15) * 8;
        int4 v = *(const int4*)&Wt[row * DIM + c8];
        *(int4*)&sW[row * LDS_PAD + c8] = v;
    }

    int nchunks = (M + DIM - 1) / DIM;
    for (int chunk = blockIdx.x; chunk < nchunks; chunk += gridDim.x) {
        int row0 = chunk * DIM;
        __syncthreads();
        for (int j = tid; j < DIM * DIM / 4; j += 256) {
            int row = j >> 5;
            int c4 = (j & 31) * 4;
            int grow = row0 + row;
            if (grow >= M) grow = M - 1;
            float4 v = *(const float4*)&A[(size_t)grow * DIM + c4];
            short4 s = make_short4(f2bf(v.x), f2bf(v.y), f2bf(v.z), f2bf(v.w));
            *(short4*)&sA[row * LDS_PAD + c4] = s;
        }
        __syncthreads();

        f32x4 acc[2][8];
#pragma unroll
        for (int i = 0; i < 2; ++i)
#pragma unroll
            for (int j = 0; j < 8; ++j) acc[i][j] = (f32x4){0.f, 0.f, 0.f, 0.f};

#pragma unroll
        for (int kt = 0; kt < 4; ++kt) {
            int k0 = kt * 32 + q * 8;
            short8 a0 = *(const short8*)&sA[(w * 32 + m) * LDS_PAD + k0];
            short8 a1 = *(const short8*)&sA[(w * 32 + 16 + m) * LDS_PAD + k0];
#pragma unroll
            for (int j = 0; j < 8; ++j) {
                short8 b = *(const short8*)&sW[(j * 16 + m) * LDS_PAD + k0];
                acc[0][j] = __builtin_amdgcn_mfma_f32_16x16x32_bf16(a0, b, acc[0][j], 0, 0, 0);
                acc[1][j] = __builtin_amdgcn_mfma_f32_16x16x32_bf16(a1, b, acc[1][j], 0, 0, 0);
            }
        }

#pragma unroll
        for (int i = 0; i < 2; ++i) {
#pragma unroll
            for (int r = 0; r < 4; ++r) {
                int row = row0 + w * 32 + i * 16 + q * 4 + r;
                if (row < M) {
#pragma unroll
                    for (int j = 0; j < 8; ++j) {
                        float v = acc[i][j][r];
                        if constexpr (sizeof(OUT) == 2)
                            C[(size_t)row * DIM + j * 16 + m] = f2bf(v);
                        else
                            C[(size_t)row * DIM + j * 16 + m] = v;
                    }
                }
            }
        }
    }
}

// ---------------------------------------------------------------------------
// CSR build (both sides jointly): count -> joint scan -> fill.
// cnt/off are over n_u+n_i concatenated; u counts sum to E, so the joint
// exclusive scan gives i-side offsets pre-shifted by E into the combined
// 2E-entry edge array ce[] (u CSR in [0,E), i CSR in [E,2E)).
// ---------------------------------------------------------------------------
__global__ __launch_bounds__(256) void k_count(const int* __restrict__ ro,
                                               const int* __restrict__ co,
                                               int* __restrict__ cnt,
                                               int n_u, int E) {
    int e = blockIdx.x * 256 + threadIdx.x;
    if (e >= E) return;
    atomicAdd(&cnt[ro[e]], 1);
    atomicAdd(&cnt[n_u + co[e]], 1);
}

__global__ __launch_bounds__(SCAN_T) void k_scan1(const int* __restrict__ cnt,
                                                  int* __restrict__ out,
                                                  int* __restrict__ tot, int n) {
    __shared__ int s[SCAN_T];
    int tid = threadIdx.x;
    int base = blockIdx.x * SCAN_C + tid * SCAN_E;
    int v[SCAN_E];
    int sum = 0;
#pragma unroll
    for (int i = 0; i < SCAN_E; ++i) {
        v[i] = (base + i < n) ? cnt[base + i] : 0;
        sum += v[i];
    }
    s[tid] = sum;
    __syncthreads();
    for (int off = 1; off < SCAN_T; off <<= 1) {
        int t = (tid >= off) ? s[tid - off] : 0;
        __syncthreads();
        s[tid] += t;
        __syncthreads();
    }
    int run = s[tid] - sum;
    if (tid == SCAN_T - 1) tot[blockIdx.x] = s[tid];
#pragma unroll
    for (int i = 0; i < SCAN_E; ++i) {
        if (base + i < n) out[base + i] = run;
        run += v[i];
    }
}

__global__ __launch_bounds__(64) void k_scan2(int* __restrict__ tot, int nchunks) {
    int lane = threadIdx.x;
    int running = 0;
    for (int c0 = 0; c0 < nchunks; c0 += 64) {
        int idx = c0 + lane;
        int orig = (idx < nchunks) ? tot[idx] : 0;
        int v = orig;
#pragma unroll
        for (int d = 1; d < 64; d <<= 1) {
            int t = __shfl_up(v, d);
            if (lane >= d) v += t;
        }
        if (idx < nchunks) tot[idx] = running + v - orig;
        running += __shfl(v, 63);
    }
}

__global__ __launch_bounds__(256) void k_scan3(int* __restrict__ off,
                                               int* __restrict__ cur,
                                               const int* __restrict__ tot,
                                               int n, int total_edges) {
    int i = blockIdx.x * 256 + threadIdx.x;
    if (i < n) {
        int v = off[i] + tot[i / SCAN_C];
        off[i] = v;
        cur[i] = v;
    }
    if (i == 0) off[n] = total_edges;
}

__global__ __launch_bounds__(256) void k_fill(const int* __restrict__ ro,
                                              const int* __restrict__ co,
                                              const float* __restrict__ va,
                                              int* __restrict__ cur,
                                              int2* __restrict__ ce,
                                              int n_u, int E) {
    int e = blockIdx.x * 256 + threadIdx.x;
    if (e >= E) return;
    int r = ro[e], c = co[e];
    int vbits = __builtin_bit_cast(int, va[e]);
    int pu = atomicAdd(&cur[r], 1);
    ce[pu] = make_int2(c, vbits);
    int pi = atomicAdd(&cur[n_u + c], 1);
    ce[pi] = make_int2(r, vbits);
}

// ---------------------------------------------------------------------------
// Gather-reduce with inline div: out[dst] += (1/(sum va + 1)) * sum va*T[src]
// T is bf16. One 32-lane half-wave per dst row; no atomics.
// ---------------------------------------------------------------------------
__global__ __launch_bounds__(256) void k_gather(const int* __restrict__ off,
                                                const int2* __restrict__ ce,
                                                const short* __restrict__ T,
                                                float* __restrict__ out,
                                                int n, int base) {
    int dst = blockIdx.x * 8 + (threadIdx.x >> 5);
    if (dst >= n) return;
    int l = threadIdx.x & 31;
    int s0 = off[base + dst], s1 = off[base + dst + 1];
    float4 acc = make_float4(0.f, 0.f, 0.f, 0.f);
    float vsum = 0.f;
    for (int j = s0; j < s1; ++j) {
        int2 e = ce[j];
        float v = __builtin_bit_cast(float, e.y);
        vsum += v;
        short4 t = *(const short4*)&T[(size_t)e.x * DIM + l * 4];
        acc.x += v * bf2f(t.x);
        acc.y += v * bf2f(t.y);
        acc.z += v * bf2f(t.z);
        acc.w += v * bf2f(t.w);
    }
    float dv = 1.0f / (vsum + 1.0f);
    float4* op = (float4*)&out[(size_t)dst * DIM + l * 4];
    float4 o = *op;
    o.x += dv * acc.x;
    o.y += dv * acc.y;
    o.z += dv * acc.z;
    o.w += dv * acc.w;
    *op = o;
}

__global__ __launch_bounds__(256) void k_leaky_relu(float* __restrict__ x, long n4) {
    long i = blockIdx.x * 256L + threadIdx.x;
    if (i >= n4) return;
    float4 v = ((float4*)x)[i];
    v.x = v.x > 0.f ? v.x : 0.01f * v.x;
    v.y = v.y > 0.f ? v.y : 0.01f * v.y;
    v.z = v.z > 0.f ? v.z : 0.01f * v.z;
    v.w = v.w > 0.f ? v.w : 0.01f * v.w;
    ((float4*)x)[i] = v;
}

// ---------------------------------------------------------------------------
static inline size_t align4(size_t x) { return (x + 3) & ~(size_t)3; }

extern "C" void kernel_launch(void* const* d_in, const int* in_sizes, int n_in,
                              void* d_out, int out_size, void* d_ws, size_t ws_size,
                              hipStream_t stream) {
    const float* u_in = (const float*)d_in[0];
    const float* i_in = (const float*)d_in[1];
    const float* Wp   = (const float*)d_in[2];
    const float* Ws   = (const float*)d_in[3];
    const float* vals = (const float*)d_in[4];
    const int*   rows = (const int*)d_in[5];
    const int*   cols = (const int*)d_in[6];

    int n_u   = in_sizes[0] / DIM;
    int n_i   = in_sizes[1] / DIM;
    int num_r = in_sizes[3] / (DIM * DIM);
    int E     = in_sizes[4] / num_r;
    int n_t   = n_u + n_i;

    size_t matu = (size_t)n_u * DIM;
    size_t mati = (size_t)n_i * DIM;
    size_t tsz  = ((n_u > n_i ? n_u : n_i)) * (size_t)DIM;

    // ---- workspace layout (4-byte words, 16 B aligned sections) ----
    float* ws = (float*)d_ws;
    size_t o = 0;
    short* T    = (short*)(ws + o); o += align4(tsz / 2 + 2);
    float* u_ws = ws + o;           o += align4(matu);
    float* i_ws = ws + o;           o += align4(mati);
    short* Wt   = (short*)(ws + o); o += align4((size_t)(1 + num_r) * DIM * DIM / 2);
    int*  cnt   = (int*)(ws + o);   o += align4(n_t);       // reused as cur
    int*  off   = (int*)(ws + o);   o += align4(n_t + 1);
    int*  tot   = (int*)(ws + o);   o += 4096;
    int2* ce    = (int2*)(ws + o);  o += align4((size_t)2 * E * 2);

    float* out_u = (float*)d_out;
    float* out_i = out_u + matu;

    // ---- weight transpose+convert (once) ----
    int wtot = (1 + num_r) * DIM * DIM;
    k_prep_w<<<(wtot + 255) / 256, 256, 0, stream>>>(Wp, Ws, Wt, num_r);
    const short* Wt_p = Wt;

    const float* u_cur = u_in;
    const float* i_cur = i_in;
    int gE  = (E + 255) / 256;
    int nch = (n_t + SCAN_C - 1) / SCAN_C;
    const int GGEMM = 512;

    for (int r = 0; r < num_r; ++r) {
        const short* Wt_r = Wt + (size_t)(1 + r) * DIM * DIM;
        const float* va = vals + (size_t)r * E;
        const int*   ro = rows + (size_t)r * E;
        const int*   co = cols + (size_t)r * E;
        int to_out = (((num_r - 1 - r) & 1) == 0);
        float* u_next = to_out ? out_u : u_ws;
        float* i_next = to_out ? out_i : i_ws;

        // ---- build both CSRs (joint scan, combined 2E edge array) ----
        hipMemsetAsync(cnt, 0, (size_t)n_t * sizeof(int), stream);
        k_count<<<gE, 256, 0, stream>>>(ro, co, cnt, n_u, E);
        k_scan1<<<nch, SCAN_T, 0, stream>>>(cnt, off, tot, n_t);
        k_scan2<<<1, 64, 0, stream>>>(tot, nch);
        k_scan3<<<(n_t + 255) / 256, 256, 0, stream>>>(off, cnt, tot, n_t, 2 * E);
        k_fill<<<gE, 256, 0, stream>>>(ro, co, va, cnt, ce, n_u, E);

        // ---- u phase: u_next = u_cur@Wp + div_u * gather(T = i_cur@Wr) ----
        k_gemm_mfma<short><<<GGEMM, 256, 0, stream>>>(i_cur, Wt_r, T, n_i);
        k_gemm_mfma<float><<<GGEMM, 256, 0, stream>>>(u_cur, Wt_p, u_next, n_u);
        k_gather<<<(n_u + 7) / 8, 256, 0, stream>>>(off, ce, T, u_next, n_u, 0);
        u_cur = u_next;

        // ---- i phase ----
        k_gemm_mfma<short><<<GGEMM, 256, 0, stream>>>(u_cur, Wt_r, T, n_u);
        k_gemm_mfma<float><<<GGEMM, 256, 0, stream>>>(i_cur, Wt_p, i_next, n_i);
        k_gather<<<(n_i + 7) / 8, 256, 0, stream>>>(off, ce, T, i_next, n_i, n_u);
        i_cur = i_next;
    }

    long n4 = (long)(matu + mati) / 4;
    k_leaky_relu<<<(int)((n4 + 255) / 256), 256, 0, stream>>>(out_u, n4);
}